// Round 1
// baseline (273.438 us; speedup 1.0000x reference)
//
#include <hip/hip_runtime.h>

// Problem constants
#define E   1024
#define SQ  2048
#define NR  4096    // N*S rows

typedef _Float16 half8 __attribute__((ext_vector_type(8)));
typedef _Float16 half4 __attribute__((ext_vector_type(4)));
typedef float    f32x4 __attribute__((ext_vector_type(4)));

#define MFMA_F16(a, b, c) __builtin_amdgcn_mfma_f32_16x16x32_f16((a), (b), (c), 0, 0, 0)

// async global->LDS, 16B per lane. LDS dest is wave-uniform base + lane*16.
__device__ __forceinline__ void async16(const void* g, void* l) {
  __builtin_amdgcn_global_load_lds((const __attribute__((address_space(1))) void*)g,
                                   (__attribute__((address_space(3))) void*)l, 16, 0, 0);
}

// -------- f32 -> f16 convert (grid sized exactly, 1024 floats / block) -----
__global__ __launch_bounds__(256) void cvtk(const float* __restrict__ in,
                                            _Float16* __restrict__ out) {
  int i = blockIdx.x * 256 + threadIdx.x;
  f32x4 v = ((const f32x4*)in)[i];
  ((half4*)out)[i] = __builtin_convertvector(v, half4);
}

// -------- GEMM: C[M,N] = A[M,K] * B[N,K]^T  (f16 in, f16 or f32+bias out) --
// 128x128 tile, BK=64, 4 waves each computing a 64x64 quadrant (4x4 MFMA frags).
// LDS rows are 128B; XOR swizzle byte ^= ((row&7)<<4) applied by pre-swizzling
// the global source chunk for global_load_lds and on the ds_read_b128 side.
template <bool OUTF32>
__global__ __launch_bounds__(256, 2)
void gemm_bt(const _Float16* __restrict__ A,
             const _Float16* __restrict__ B0, const _Float16* __restrict__ B1,
             const _Float16* __restrict__ B2,
             _Float16* __restrict__ C0, _Float16* __restrict__ C1,
             _Float16* __restrict__ C2,
             float* __restrict__ Cf, const float* __restrict__ bias,
             int M, int N, int K)
{
  const int z = blockIdx.z;
  const _Float16* B = (z == 0) ? B0 : ((z == 1) ? B1 : B2);
  _Float16* C = (z == 0) ? C0 : ((z == 1) ? C1 : C2);
  __shared__ _Float16 As[128 * 64];
  __shared__ _Float16 Bs[128 * 64];
  const int tid = threadIdx.x;
  const int w = tid >> 6, lane = tid & 63;
  const int lr = lane & 15, lg = lane >> 4;
  const int l8 = lane >> 3, l7 = lane & 7;
  const int gch = l7 ^ (l8 & 7);              // pre-swizzled global chunk
  const int tm = blockIdx.x * 128, tn = blockIdx.y * 128;
  const int wr = w >> 1, wc = w & 1;
  const int sl7 = lr & 7;

  const f32x4 zv = {0.f, 0.f, 0.f, 0.f};
  f32x4 acc[4][4];
  #pragma unroll
  for (int mi = 0; mi < 4; mi++)
    #pragma unroll
    for (int ni = 0; ni < 4; ni++) acc[mi][ni] = zv;

  for (int ks = 0; ks < K; ks += 64) {
    #pragma unroll
    for (int ci = 0; ci < 4; ci++) {          // A tile: 16 chunks of 1KB
      int c = w + ci * 4;
      async16(A + (size_t)(tm + c * 8 + l8) * K + ks + gch * 8, (void*)(As + c * 512));
    }
    #pragma unroll
    for (int ci = 0; ci < 4; ci++) {          // B tile
      int c = w + ci * 4;
      async16(B + (size_t)(tn + c * 8 + l8) * K + ks + gch * 8, (void*)(Bs + c * 512));
    }
    __syncthreads();
    #pragma unroll
    for (int kk = 0; kk < 2; kk++) {
      const int sl = ((kk * 4 + lg) ^ sl7) << 4;
      half8 af[4], bf[4];
      #pragma unroll
      for (int mi = 0; mi < 4; mi++)
        af[mi] = *(const half8*)((const char*)As + (wr * 64 + mi * 16 + lr) * 128 + sl);
      #pragma unroll
      for (int ni = 0; ni < 4; ni++)
        bf[ni] = *(const half8*)((const char*)Bs + (wc * 64 + ni * 16 + lr) * 128 + sl);
      #pragma unroll
      for (int mi = 0; mi < 4; mi++)
        #pragma unroll
        for (int ni = 0; ni < 4; ni++)
          acc[mi][ni] = MFMA_F16(af[mi], bf[ni], acc[mi][ni]);
    }
    __syncthreads();
  }
  // epilogue: D lane layout col = lane&15, row = 4*(lane>>4)+reg
  #pragma unroll
  for (int mi = 0; mi < 4; mi++) {
    const int row = tm + wr * 64 + mi * 16 + 4 * lg;
    #pragma unroll
    for (int ni = 0; ni < 4; ni++) {
      const int col = tn + wc * 64 + ni * 16 + lr;
      #pragma unroll
      for (int j = 0; j < 4; j++) {
        if constexpr (OUTF32)
          Cf[(size_t)(row + j) * N + col] = acc[mi][ni][j] + bias[col];
        else
          C[(size_t)(row + j) * N + col] = (_Float16)acc[mi][ni][j];
      }
    }
  }
}

// -------- Flash attention: one (n,h), 128 Q-rows per block; 4 waves x 32 rows
// K LDS row-major [64][64] (swizzled), V LDS transposed [d][kv] (swizzled) so
// both QK^T B-frags and PV B-frags are conflict-free ds_read_b128.
__global__ __launch_bounds__(256, 2)
void attn_kernel(const _Float16* __restrict__ Q, const _Float16* __restrict__ Kg,
                 const _Float16* __restrict__ Vg, _Float16* __restrict__ Og)
{
  __shared__ _Float16 Ks[2][64 * 64];
  __shared__ _Float16 Vt[2][64 * 64];
  __shared__ _Float16 Ps[4][32 * 64];
  const int tid = threadIdx.x;
  const int w = tid >> 6, lane = tid & 63;
  const int lr = lane & 15, lg = lane >> 4;
  const int l8 = lane >> 3, l7 = lane & 7;
  const int nb = blockIdx.y;
  const size_t hb = (size_t)(nb >> 4) * SQ * E + (size_t)(nb & 15) * 64;
  const int qbase = blockIdx.x * 128 + w * 32;
  const int sl7 = lr & 7;

  // Q fragments in registers, pre-scaled by 1/sqrt(E) = 1/32
  half8 qf[2][2];
  #pragma unroll
  for (int rf = 0; rf < 2; rf++)
    #pragma unroll
    for (int kk = 0; kk < 2; kk++) {
      half8 v = *(const half8*)(Q + hb + (size_t)(qbase + rf * 16 + lr) * E + kk * 32 + lg * 8);
      qf[rf][kk] = v * (_Float16)0.03125f;
    }

  const f32x4 zv = {0.f, 0.f, 0.f, 0.f};
  f32x4 o[2][4];
  float ms[2][4], ls[2][4];
  #pragma unroll
  for (int rf = 0; rf < 2; rf++)
    #pragma unroll
    for (int jj = 0; jj < 4; jj++) { ms[rf][jj] = -1e30f; ls[rf][jj] = 0.f; }
  #pragma unroll
  for (int rf = 0; rf < 2; rf++)
    #pragma unroll
    for (int ni = 0; ni < 4; ni++) o[rf][ni] = zv;

  half8 vr[2];
  // prologue: stage tile 0 into buffer 0
  {
    #pragma unroll
    for (int i = 0; i < 2; i++) {
      int c = tid + 256 * i; int kv = c >> 3, d0 = (c & 7) * 8;
      vr[i] = *(const half8*)(Vg + hb + (size_t)kv * E + d0);
    }
    #pragma unroll
    for (int ci = 0; ci < 2; ci++) {
      int c = w + ci * 4;
      async16(Kg + hb + (size_t)(c * 8 + l8) * E + (l7 ^ (l8 & 7)) * 8, (void*)(Ks[0] + c * 512));
    }
    #pragma unroll
    for (int i = 0; i < 2; i++) {
      int c = tid + 256 * i; int kv = c >> 3, d0 = (c & 7) * 8;
      #pragma unroll
      for (int j = 0; j < 8; j++) {
        int d = d0 + j;
        *(_Float16*)((char*)Vt[0] + d * 128 + ((kv * 2) ^ ((d & 7) << 4))) = vr[i][j];
      }
    }
  }
  __syncthreads();

  int cur = 0;
  for (int t = 0; t < 32; t++) {
    const bool more = (t < 31);
    const int kvb_next = (t + 1) * 64;
    if (more) {   // issue next-tile loads early (hide under compute)
      #pragma unroll
      for (int i = 0; i < 2; i++) {
        int c = tid + 256 * i; int kv = c >> 3, d0 = (c & 7) * 8;
        vr[i] = *(const half8*)(Vg + hb + (size_t)(kvb_next + kv) * E + d0);
      }
      #pragma unroll
      for (int ci = 0; ci < 2; ci++) {
        int c = w + ci * 4;
        async16(Kg + hb + (size_t)(kvb_next + c * 8 + l8) * E + (l7 ^ (l8 & 7)) * 8,
                (void*)(Ks[cur ^ 1] + c * 512));
      }
    }
    // S = (Q/32) K^T   (already scaled)
    f32x4 s[2][4];
    #pragma unroll
    for (int rf = 0; rf < 2; rf++)
      #pragma unroll
      for (int ni = 0; ni < 4; ni++) s[rf][ni] = zv;
    #pragma unroll
    for (int kk = 0; kk < 2; kk++) {
      const int sl = ((kk * 4 + lg) ^ sl7) << 4;
      half8 kf[4];
      #pragma unroll
      for (int ni = 0; ni < 4; ni++)
        kf[ni] = *(const half8*)((const char*)Ks[cur] + (ni * 16 + lr) * 128 + sl);
      #pragma unroll
      for (int rf = 0; rf < 2; rf++)
        #pragma unroll
        for (int ni = 0; ni < 4; ni++)
          s[rf][ni] = MFMA_F16(qf[rf][kk], kf[ni], s[rf][ni]);
    }
    // online softmax; rows live in 16-lane groups -> shfl_xor masks 1,2,4,8
    #pragma unroll
    for (int rf = 0; rf < 2; rf++) {
      #pragma unroll
      for (int jj = 0; jj < 4; jj++) {
        float s0 = s[rf][0][jj], s1 = s[rf][1][jj], s2 = s[rf][2][jj], s3 = s[rf][3][jj];
        float mx = fmaxf(fmaxf(s0, s1), fmaxf(s2, s3));
        #pragma unroll
        for (int mk = 1; mk < 16; mk <<= 1) mx = fmaxf(mx, __shfl_xor(mx, mk));
        float mold = ms[rf][jj];
        float mnew = fmaxf(mold, mx);
        float corr = __expf(mold - mnew);
        float p0 = __expf(s0 - mnew), p1 = __expf(s1 - mnew);
        float p2 = __expf(s2 - mnew), p3 = __expf(s3 - mnew);
        float rs = (p0 + p1) + (p2 + p3);
        #pragma unroll
        for (int mk = 1; mk < 16; mk <<= 1) rs += __shfl_xor(rs, mk);
        ms[rf][jj] = mnew;
        ls[rf][jj] = ls[rf][jj] * corr + rs;
        #pragma unroll
        for (int ni = 0; ni < 4; ni++) o[rf][ni][jj] *= corr;
        const int prow = rf * 16 + 4 * lg + jj;
        char* pb = (char*)Ps[w] + prow * 128;
        const int rswz = (prow & 7) << 4;
        *(_Float16*)(pb + ((     lr * 2) ^ rswz)) = (_Float16)p0;
        *(_Float16*)(pb + ((32 + lr * 2) ^ rswz)) = (_Float16)p1;
        *(_Float16*)(pb + ((64 + lr * 2) ^ rswz)) = (_Float16)p2;
        *(_Float16*)(pb + ((96 + lr * 2) ^ rswz)) = (_Float16)p3;
      }
    }
    // O += P * V   (A-frags from per-wave Ps, B-frags from transposed Vt)
    #pragma unroll
    for (int kk = 0; kk < 2; kk++) {
      const int sl = ((kk * 4 + lg) ^ sl7) << 4;
      half8 pa[2], vf[4];
      #pragma unroll
      for (int mi = 0; mi < 2; mi++)
        pa[mi] = *(const half8*)((const char*)Ps[w] + (mi * 16 + lr) * 128 + sl);
      #pragma unroll
      for (int ni = 0; ni < 4; ni++)
        vf[ni] = *(const half8*)((const char*)Vt[cur] + (ni * 16 + lr) * 128 + sl);
      #pragma unroll
      for (int mi = 0; mi < 2; mi++)
        #pragma unroll
        for (int ni = 0; ni < 4; ni++)
          o[mi][ni] = MFMA_F16(pa[mi], vf[ni], o[mi][ni]);
    }
    if (more) {   // write next V tile transposed into LDS
      #pragma unroll
      for (int i = 0; i < 2; i++) {
        int c = tid + 256 * i; int kv = c >> 3, d0 = (c & 7) * 8;
        #pragma unroll
        for (int j = 0; j < 8; j++) {
          int d = d0 + j;
          *(_Float16*)((char*)Vt[cur ^ 1] + d * 128 + ((kv * 2) ^ ((d & 7) << 4))) = vr[i][j];
        }
      }
    }
    __syncthreads();
    cur ^= 1;
  }
  // epilogue: O /= l
  #pragma unroll
  for (int rf = 0; rf < 2; rf++) {
    #pragma unroll
    for (int jj = 0; jj < 4; jj++) {
      const float inv = 1.0f / ls[rf][jj];
      const int row = qbase + rf * 16 + 4 * lg + jj;
      #pragma unroll
      for (int ni = 0; ni < 4; ni++)
        Og[hb + (size_t)row * E + ni * 16 + lr] = (_Float16)(o[rf][ni][jj] * inv);
    }
  }
}

extern "C" void kernel_launch(void* const* d_in, const int* in_sizes, int n_in,
                              void* d_out, int out_size, void* d_ws, size_t ws_size,
                              hipStream_t stream)
{
  const float* x  = (const float*)d_in[0];
  const float* Wq = (const float*)d_in[1];
  const float* Wk = (const float*)d_in[2];
  const float* Wv = (const float*)d_in[3];
  const float* Wo = (const float*)d_in[4];
  const float* bo = (const float*)d_in[5];
  char* ws = (char*)d_ws;
  const size_t MB = 1024u * 1024u;
  // workspace layout (32 MiB): xh | Wq/Wk/Wv/Wo f16 | Vh | Oh
  _Float16* xh  = (_Float16*)(ws);
  _Float16* Wqh = (_Float16*)(ws + 8 * MB);
  _Float16* Wkh = (_Float16*)(ws + 10 * MB);
  _Float16* Wvh = (_Float16*)(ws + 12 * MB);
  _Float16* Woh = (_Float16*)(ws + 14 * MB);
  _Float16* Vh  = (_Float16*)(ws + 16 * MB);
  _Float16* Oh  = (_Float16*)(ws + 24 * MB);
  // Q and K parked in d_out (16 MiB); dead before the final GEMM overwrites it
  _Float16* Qh  = (_Float16*)(d_out);
  _Float16* Kh  = (_Float16*)((char*)d_out + 8 * MB);
  float* Y = (float*)d_out;

  cvtk<<<4096, 256, 0, stream>>>(x,  xh);
  cvtk<<<1024, 256, 0, stream>>>(Wq, Wqh);
  cvtk<<<1024, 256, 0, stream>>>(Wk, Wkh);
  cvtk<<<1024, 256, 0, stream>>>(Wv, Wvh);
  cvtk<<<1024, 256, 0, stream>>>(Wo, Woh);

  // fused QKV projection: z selects weight/output
  gemm_bt<false><<<dim3(32, 8, 3), 256, 0, stream>>>(
      xh, Wqh, Wkh, Wvh, Qh, Kh, Vh, nullptr, nullptr, NR, E, E);

  attn_kernel<<<dim3(16, 32), 256, 0, stream>>>(Qh, Kh, Vh, Oh);

  // output projection + bias, f32 out
  gemm_bt<true><<<dim3(32, 8, 1), 256, 0, stream>>>(
      Oh, Woh, Woh, Woh, nullptr, nullptr, nullptr, Y, bo, NR, E, E);
}

// Round 2
// 203.002 us; speedup vs baseline: 1.3470x; 1.3470x over previous
//
#include <hip/hip_runtime.h>

// Problem constants
#define E   1024
#define SQ  2048
#define NR  4096    // N*S rows

typedef _Float16 half8 __attribute__((ext_vector_type(8)));
typedef _Float16 half4 __attribute__((ext_vector_type(4)));
typedef float    f32x4 __attribute__((ext_vector_type(4)));

#define MFMA_F16(a, b, c) __builtin_amdgcn_mfma_f32_16x16x32_f16((a), (b), (c), 0, 0, 0)

// async global->LDS, 16B per lane. LDS dest is wave-uniform base + lane*16.
__device__ __forceinline__ void async16(const void* g, void* l) {
  __builtin_amdgcn_global_load_lds((const __attribute__((address_space(1))) void*)g,
                                   (__attribute__((address_space(3))) void*)l, 16, 0, 0);
}

__device__ __forceinline__ float bperm_f(int srclane, float v) {
  return __int_as_float(__builtin_amdgcn_ds_bpermute(srclane << 2, __float_as_int(v)));
}

// -------- f32 -> f16 convert, all 5 tensors in one launch ------------------
__global__ __launch_bounds__(256)
void cvtall(const float* __restrict__ x, const float* __restrict__ wq,
            const float* __restrict__ wk, const float* __restrict__ wv,
            const float* __restrict__ wo,
            _Float16* __restrict__ xh, _Float16* __restrict__ wqh,
            _Float16* __restrict__ wkh, _Float16* __restrict__ wvh,
            _Float16* __restrict__ woh) {
  int b = blockIdx.x;
  const float* src; _Float16* dst; int off;
  if (b < 4096)      { src = x;  dst = xh;  off = b; }
  else if (b < 5120) { src = wq; dst = wqh; off = b - 4096; }
  else if (b < 6144) { src = wk; dst = wkh; off = b - 5120; }
  else if (b < 7168) { src = wv; dst = wvh; off = b - 6144; }
  else               { src = wo; dst = woh; off = b - 7168; }
  int i = off * 256 + threadIdx.x;
  f32x4 v = ((const f32x4*)src)[i];
  ((half4*)dst)[i] = __builtin_convertvector(v, half4);
}

// -------- GEMM: C[M,N] = A[M,K] * B[N,K]^T  (f16 in, f16 or f32+bias out) --
template <bool OUTF32>
__global__ __launch_bounds__(256, 2)
void gemm_bt(const _Float16* __restrict__ A,
             const _Float16* __restrict__ B0, const _Float16* __restrict__ B1,
             const _Float16* __restrict__ B2,
             _Float16* __restrict__ C0, _Float16* __restrict__ C1,
             _Float16* __restrict__ C2,
             float* __restrict__ Cf, const float* __restrict__ bias,
             int M, int N, int K)
{
  const int z = blockIdx.z;
  const _Float16* B = (z == 0) ? B0 : ((z == 1) ? B1 : B2);
  _Float16* C = (z == 0) ? C0 : ((z == 1) ? C1 : C2);
  __shared__ _Float16 As[128 * 64];
  __shared__ _Float16 Bs[128 * 64];
  const int tid = threadIdx.x;
  const int w = tid >> 6, lane = tid & 63;
  const int lr = lane & 15, lg = lane >> 4;
  const int l8 = lane >> 3, l7 = lane & 7;
  const int gch = l7 ^ (l8 & 7);
  const int tm = blockIdx.x * 128, tn = blockIdx.y * 128;
  const int wr = w >> 1, wc = w & 1;
  const int sl7 = lr & 7;

  const f32x4 zv = {0.f, 0.f, 0.f, 0.f};
  f32x4 acc[4][4];
  #pragma unroll
  for (int mi = 0; mi < 4; mi++)
    #pragma unroll
    for (int ni = 0; ni < 4; ni++) acc[mi][ni] = zv;

  for (int ks = 0; ks < K; ks += 64) {
    #pragma unroll
    for (int ci = 0; ci < 4; ci++) {
      int c = w + ci * 4;
      async16(A + (size_t)(tm + c * 8 + l8) * K + ks + gch * 8, (void*)(As + c * 512));
    }
    #pragma unroll
    for (int ci = 0; ci < 4; ci++) {
      int c = w + ci * 4;
      async16(B + (size_t)(tn + c * 8 + l8) * K + ks + gch * 8, (void*)(Bs + c * 512));
    }
    __syncthreads();
    #pragma unroll
    for (int kk = 0; kk < 2; kk++) {
      const int sl = ((kk * 4 + lg) ^ sl7) << 4;
      half8 af[4], bf[4];
      #pragma unroll
      for (int mi = 0; mi < 4; mi++)
        af[mi] = *(const half8*)((const char*)As + (wr * 64 + mi * 16 + lr) * 128 + sl);
      #pragma unroll
      for (int ni = 0; ni < 4; ni++)
        bf[ni] = *(const half8*)((const char*)Bs + (wc * 64 + ni * 16 + lr) * 128 + sl);
      #pragma unroll
      for (int mi = 0; mi < 4; mi++)
        #pragma unroll
        for (int ni = 0; ni < 4; ni++)
          acc[mi][ni] = MFMA_F16(af[mi], bf[ni], acc[mi][ni]);
    }
    __syncthreads();
  }
  #pragma unroll
  for (int mi = 0; mi < 4; mi++) {
    const int row = tm + wr * 64 + mi * 16 + 4 * lg;
    #pragma unroll
    for (int ni = 0; ni < 4; ni++) {
      const int col = tn + wc * 64 + ni * 16 + lr;
      #pragma unroll
      for (int j = 0; j < 4; j++) {
        if constexpr (OUTF32)
          Cf[(size_t)(row + j) * N + col] = acc[mi][ni][j] + bias[col];
        else
          C[(size_t)(row + j) * N + col] = (_Float16)acc[mi][ni][j];
      }
    }
  }
}

// -------- V transpose+permute: Vg2[(n*16+h)*64 + d][s0 + c] = V[n,s0+kv(c),h*64+d]
// c = 32kk + 8lg + 4h' + jr  <->  kv = 32kk + 16h' + 4lg + jr
// so the attn PV B-fragment (lane lg, k-slots j'=0..7 at kk) reads 16B contiguous.
__global__ __launch_bounds__(256)
void vtrans(const _Float16* __restrict__ V, _Float16* __restrict__ Vg2) {
  __shared__ _Float16 Vl[64][72];
  const int tid = threadIdx.x;
  const int s0 = blockIdx.x * 64;
  const int nb = blockIdx.y;
  const _Float16* src = V + (size_t)(nb >> 4) * SQ * E + (size_t)s0 * E + (nb & 15) * 64;
  #pragma unroll
  for (int i = 0; i < 2; i++) {
    int c = tid + 256 * i; int s = c >> 3, d0 = (c & 7) * 8;
    *(half8*)(&Vl[s][d0]) = *(const half8*)(src + (size_t)s * E + d0);
  }
  __syncthreads();
  #pragma unroll
  for (int i = 0; i < 2; i++) {
    int c = tid + 256 * i; int d = c >> 3, m = c & 7;
    half8 o;
    #pragma unroll
    for (int r = 0; r < 8; r++) {
      int p = 8 * m + r;
      int kv = (p & 32) | (((p >> 2) & 1) << 4) | (((p >> 3) & 3) << 2) | (p & 3);
      o[r] = Vl[kv][d];
    }
    *(half8*)(Vg2 + ((size_t)nb * 64 + d) * SQ + s0 + 8 * m) = o;
  }
}

// -------- Flash attention, swapped-operand form ----------------------------
// S^T = mfma(K, Q): lane owns q-col = lane&15, kv rows 16ni+4lg+j -> softmax
// is in-lane tree + shfl_xor(16,32). P stays in registers; PV uses a permuted
// k-mapping matched by Vg2's column permutation. K and V both staged via
// global_load_lds with pre-swizzled source; ds_read_b128 conflict-free.
__global__ __launch_bounds__(256, 2)
void attn_kernel(const _Float16* __restrict__ Q, const _Float16* __restrict__ Kg,
                 const _Float16* __restrict__ Vg2, _Float16* __restrict__ Og)
{
  __shared__ _Float16 Ks[2][64 * 64];
  __shared__ _Float16 Vt[2][64 * 64];
  const int tid = threadIdx.x;
  const int w = tid >> 6, lane = tid & 63;
  const int lr = lane & 15, lg = lane >> 4;
  const int l8 = lane >> 3, l7 = lane & 7;
  const int nb = blockIdx.y;
  const size_t hb  = (size_t)(nb >> 4) * SQ * E + (size_t)(nb & 15) * 64;
  const size_t hb2 = (size_t)nb * 64 * SQ;
  const int qbase = blockIdx.x * 128 + w * 32;
  const int gsl = (l7 ^ (l8 & 7)) * 8;    // pre-swizzled global slot (elems)
  const int sl7 = lr & 7;

  // Q B-frags in registers, pre-scaled by 1/sqrt(E) = 1/32
  half8 qf[2][2];
  #pragma unroll
  for (int qi = 0; qi < 2; qi++)
    #pragma unroll
    for (int kd = 0; kd < 2; kd++) {
      half8 v = *(const half8*)(Q + hb + (size_t)(qbase + qi * 16 + lr) * E + kd * 32 + lg * 8);
      qf[qi][kd] = v * (_Float16)0.03125f;
    }

  const f32x4 zv = {0.f, 0.f, 0.f, 0.f};
  f32x4 o[2][4];
  float ms[2] = {-1e30f, -1e30f}, ls[2] = {0.f, 0.f};
  #pragma unroll
  for (int mi = 0; mi < 2; mi++)
    #pragma unroll
    for (int nd = 0; nd < 4; nd++) o[mi][nd] = zv;

  // prologue: stage tile 0 into buffer 0
  #pragma unroll
  for (int ci = 0; ci < 2; ci++) {
    int c = w + ci * 4;
    async16(Kg  + hb  + (size_t)(c * 8 + l8) * E  + gsl, (void*)(Ks[0] + c * 512));
    async16(Vg2 + hb2 + (size_t)(c * 8 + l8) * SQ + gsl, (void*)(Vt[0] + c * 512));
  }
  __syncthreads();

  int cur = 0;
  for (int t = 0; t < 32; t++) {
    if (t < 31) {     // issue next-tile staging early
      const int kvb = (t + 1) * 64;
      #pragma unroll
      for (int ci = 0; ci < 2; ci++) {
        int c = w + ci * 4;
        async16(Kg  + hb  + (size_t)(kvb + c * 8 + l8) * E + gsl, (void*)(Ks[cur ^ 1] + c * 512));
        async16(Vg2 + hb2 + (size_t)(c * 8 + l8) * SQ + kvb + gsl, (void*)(Vt[cur ^ 1] + c * 512));
      }
    }
    // S^T = K Q^T (scaled): s[qi][ni] rows kv=16ni+4lg+j, col q=16qi+lr
    f32x4 s[2][4];
    #pragma unroll
    for (int qi = 0; qi < 2; qi++)
      #pragma unroll
      for (int ni = 0; ni < 4; ni++) s[qi][ni] = zv;
    #pragma unroll
    for (int kd = 0; kd < 2; kd++) {
      const int sl = ((kd * 4 + lg) ^ sl7) << 4;
      half8 kf[4];
      #pragma unroll
      for (int ni = 0; ni < 4; ni++)
        kf[ni] = *(const half8*)((const char*)Ks[cur] + (ni * 16 + lr) * 128 + sl);
      #pragma unroll
      for (int qi = 0; qi < 2; qi++)
        #pragma unroll
        for (int ni = 0; ni < 4; ni++)
          s[qi][ni] = MFMA_F16(kf[ni], qf[qi][kd], s[qi][ni]);
    }
    // online softmax: in-lane 16-value tree + shfl over the 4 lg replicas
    float corr[2];
    #pragma unroll
    for (int qi = 0; qi < 2; qi++) {
      float m0 = fmaxf(fmaxf(s[qi][0][0], s[qi][0][1]), fmaxf(s[qi][0][2], s[qi][0][3]));
      float m1 = fmaxf(fmaxf(s[qi][1][0], s[qi][1][1]), fmaxf(s[qi][1][2], s[qi][1][3]));
      float m2 = fmaxf(fmaxf(s[qi][2][0], s[qi][2][1]), fmaxf(s[qi][2][2], s[qi][2][3]));
      float m3 = fmaxf(fmaxf(s[qi][3][0], s[qi][3][1]), fmaxf(s[qi][3][2], s[qi][3][3]));
      float mx = fmaxf(fmaxf(m0, m1), fmaxf(m2, m3));
      mx = fmaxf(mx, __shfl_xor(mx, 16));
      mx = fmaxf(mx, __shfl_xor(mx, 32));
      float mnew = fmaxf(ms[qi], mx);
      float c = __expf(ms[qi] - mnew);
      corr[qi] = c;
      float rs = 0.f;
      #pragma unroll
      for (int ni = 0; ni < 4; ni++)
        #pragma unroll
        for (int jr = 0; jr < 4; jr++) {
          float p = __expf(s[qi][ni][jr] - mnew);
          s[qi][ni][jr] = p;
          rs += p;
        }
      rs += __shfl_xor(rs, 16);
      rs += __shfl_xor(rs, 32);
      ls[qi] = ls[qi] * c + rs;
      ms[qi] = mnew;
    }
    // rescale O: corr lives at lane (q&15); O-row q = 16mi+4lg+jr
    #pragma unroll
    for (int mi = 0; mi < 2; mi++)
      #pragma unroll
      for (int jr = 0; jr < 4; jr++) {
        float c4 = bperm_f(4 * lg + jr, corr[mi]);
        #pragma unroll
        for (int nd = 0; nd < 4; nd++) o[mi][nd][jr] *= c4;
      }
    // pack P A-frags fully in-lane: k-slot j' at kk -> kv = 32kk+16(j'>>2)+4lg+(j'&3)
    half8 pa[2][2];
    #pragma unroll
    for (int mi = 0; mi < 2; mi++)
      #pragma unroll
      for (int kk = 0; kk < 2; kk++)
        #pragma unroll
        for (int j2 = 0; j2 < 8; j2++)
          pa[mi][kk][j2] = (_Float16)s[mi][2 * kk + (j2 >> 2)][j2 & 3];
    // O += P V  (B-frags from permuted Vt; same read pattern as kf)
    #pragma unroll
    for (int kk = 0; kk < 2; kk++) {
      const int sl = ((kk * 4 + lg) ^ sl7) << 4;
      half8 vf[4];
      #pragma unroll
      for (int nd = 0; nd < 4; nd++)
        vf[nd] = *(const half8*)((const char*)Vt[cur] + (nd * 16 + lr) * 128 + sl);
      #pragma unroll
      for (int mi = 0; mi < 2; mi++)
        #pragma unroll
        for (int nd = 0; nd < 4; nd++)
          o[mi][nd] = MFMA_F16(pa[mi][kk], vf[nd], o[mi][nd]);
    }
    __syncthreads();
    cur ^= 1;
  }
  // epilogue: O /= l (1/l redistributed like corr)
  #pragma unroll
  for (int mi = 0; mi < 2; mi++) {
    float li = 1.0f / ls[mi];
    #pragma unroll
    for (int jr = 0; jr < 4; jr++) {
      float lv = bperm_f(4 * lg + jr, li);
      const int row = qbase + mi * 16 + 4 * lg + jr;
      #pragma unroll
      for (int nd = 0; nd < 4; nd++)
        Og[hb + (size_t)row * E + nd * 16 + lr] = (_Float16)(o[mi][nd][jr] * lv);
    }
  }
}

extern "C" void kernel_launch(void* const* d_in, const int* in_sizes, int n_in,
                              void* d_out, int out_size, void* d_ws, size_t ws_size,
                              hipStream_t stream)
{
  const float* x  = (const float*)d_in[0];
  const float* Wq = (const float*)d_in[1];
  const float* Wk = (const float*)d_in[2];
  const float* Wv = (const float*)d_in[3];
  const float* Wo = (const float*)d_in[4];
  const float* bo = (const float*)d_in[5];
  char* ws = (char*)d_ws;
  const size_t MB = 1024u * 1024u;
  // ws layout (32 MiB): [0,8) xh, later reused as Vg2 | [8,16) weights f16
  // | [16,24) Vh | [24,32) Oh.   Q,K parked in d_out (dead before final GEMM).
  _Float16* xh  = (_Float16*)(ws);
  _Float16* Vg2 = (_Float16*)(ws);            // overlays xh after QKV GEMM
  _Float16* Wqh = (_Float16*)(ws + 8 * MB);
  _Float16* Wkh = (_Float16*)(ws + 10 * MB);
  _Float16* Wvh = (_Float16*)(ws + 12 * MB);
  _Float16* Woh = (_Float16*)(ws + 14 * MB);
  _Float16* Vh  = (_Float16*)(ws + 16 * MB);
  _Float16* Oh  = (_Float16*)(ws + 24 * MB);
  _Float16* Qh  = (_Float16*)(d_out);
  _Float16* Kh  = (_Float16*)((char*)d_out + 8 * MB);
  float* Y = (float*)d_out;

  cvtall<<<8192, 256, 0, stream>>>(x, Wq, Wk, Wv, Wo, xh, Wqh, Wkh, Wvh, Woh);

  gemm_bt<false><<<dim3(32, 8, 3), 256, 0, stream>>>(
      xh, Wqh, Wkh, Wvh, Qh, Kh, Vh, nullptr, nullptr, NR, E, E);

  vtrans<<<dim3(32, 32), 256, 0, stream>>>(Vh, Vg2);

  attn_kernel<<<dim3(16, 32), 256, 0, stream>>>(Qh, Kh, Vg2, Oh);

  gemm_bt<true><<<dim3(32, 8, 1), 256, 0, stream>>>(
      Oh, Woh, Woh, Woh, nullptr, nullptr, nullptr, Y, bo, NR, E, E);
}

// Round 5
// 186.686 us; speedup vs baseline: 1.4647x; 1.0874x over previous
//
#include <hip/hip_runtime.h>

// Problem constants
#define E   1024
#define SQ  2048
#define NR  4096    // N*S rows

typedef _Float16 half8  __attribute__((ext_vector_type(8)));
typedef _Float16 half4  __attribute__((ext_vector_type(4)));
typedef __fp16   fp16x2 __attribute__((ext_vector_type(2)));
typedef float    f32x4  __attribute__((ext_vector_type(4)));

#define MFMA_F16(a, b, c) __builtin_amdgcn_mfma_f32_16x16x32_f16((a), (b), (c), 0, 0, 0)

#if __has_builtin(__builtin_amdgcn_exp2f)
#define EXP2(x) __builtin_amdgcn_exp2f(x)
#else
#define EXP2(x) exp2f(x)
#endif

// Q pre-scale: (1/sqrt(E)) * log2(e) so softmax runs in exp2 domain
#define QSCALE 0.04508422002778011f

// async global->LDS, 16B per lane. LDS dest is wave-uniform base + lane*16.
__device__ __forceinline__ void async16(const void* g, void* l) {
  __builtin_amdgcn_global_load_lds((const __attribute__((address_space(1))) void*)g,
                                   (__attribute__((address_space(3))) void*)l, 16, 0, 0);
}

__device__ __forceinline__ float bperm_f(int srclane, float v) {
  return __int_as_float(__builtin_amdgcn_ds_bpermute(srclane << 2, __float_as_int(v)));
}

// -------- f32 -> f16 convert, all 5 tensors in one launch ------------------
__global__ __launch_bounds__(256)
void cvtall(const float* __restrict__ x, const float* __restrict__ wq,
            const float* __restrict__ wk, const float* __restrict__ wv,
            const float* __restrict__ wo,
            _Float16* __restrict__ xh, _Float16* __restrict__ wqh,
            _Float16* __restrict__ wkh, _Float16* __restrict__ wvh,
            _Float16* __restrict__ woh) {
  int b = blockIdx.x;
  const float* src; _Float16* dst; int off;
  if (b < 4096)      { src = x;  dst = xh;  off = b; }
  else if (b < 5120) { src = wq; dst = wqh; off = b - 4096; }
  else if (b < 6144) { src = wk; dst = wkh; off = b - 5120; }
  else if (b < 7168) { src = wv; dst = wvh; off = b - 6144; }
  else               { src = wo; dst = woh; off = b - 7168; }
  int i = off * 256 + threadIdx.x;
  f32x4 v = ((const f32x4*)src)[i];
  ((half4*)dst)[i] = __builtin_convertvector(v, half4);
}

// -------- QKV GEMM: C[M,N] = A[M,K] * B[N,K]^T, 128x128 tile ---------------
// z=0: Q (scaled by QSCALE), z=1: K, z=2: V written transposed+permuted into
// Vg2[(n*16+h)*64 + d][s0 + c] where c = 32kk+8lg+4h'+jr <-> kv = 32kk+16h'+4lg+jr
// (the permutation the attn PV k-slot mapping expects).
__global__ __launch_bounds__(256, 2)
void gemm_qkv(const _Float16* __restrict__ A,
              const _Float16* __restrict__ B0, const _Float16* __restrict__ B1,
              const _Float16* __restrict__ B2,
              _Float16* __restrict__ C0, _Float16* __restrict__ C1,
              _Float16* __restrict__ Vg2,
              int M, int N, int K)
{
  const int z = blockIdx.z;
  const _Float16* B = (z == 0) ? B0 : ((z == 1) ? B1 : B2);
  __shared__ _Float16 As[128 * 64];
  __shared__ _Float16 Bs[128 * 64];
  const int tid = threadIdx.x;
  const int w = tid >> 6, lane = tid & 63;
  const int lr = lane & 15, lg = lane >> 4;
  const int l8 = lane >> 3, l7 = lane & 7;
  const int gch = l7 ^ (l8 & 7);
  const int tm = blockIdx.x * 128, tn = blockIdx.y * 128;
  const int wr = w >> 1, wc = w & 1;
  const int sl7 = lr & 7;

  const f32x4 zv = {0.f, 0.f, 0.f, 0.f};
  f32x4 acc[4][4];
  #pragma unroll
  for (int mi = 0; mi < 4; mi++)
    #pragma unroll
    for (int ni = 0; ni < 4; ni++) acc[mi][ni] = zv;

  for (int ks = 0; ks < K; ks += 64) {
    #pragma unroll
    for (int ci = 0; ci < 4; ci++) {
      int c = w + ci * 4;
      async16(A + (size_t)(tm + c * 8 + l8) * K + ks + gch * 8, (void*)(As + c * 512));
    }
    #pragma unroll
    for (int ci = 0; ci < 4; ci++) {
      int c = w + ci * 4;
      async16(B + (size_t)(tn + c * 8 + l8) * K + ks + gch * 8, (void*)(Bs + c * 512));
    }
    __syncthreads();
    #pragma unroll
    for (int kk = 0; kk < 2; kk++) {
      const int sl = ((kk * 4 + lg) ^ sl7) << 4;
      half8 af[4], bf[4];
      #pragma unroll
      for (int mi = 0; mi < 4; mi++)
        af[mi] = *(const half8*)((const char*)As + (wr * 64 + mi * 16 + lr) * 128 + sl);
      #pragma unroll
      for (int ni = 0; ni < 4; ni++)
        bf[ni] = *(const half8*)((const char*)Bs + (wc * 64 + ni * 16 + lr) * 128 + sl);
      #pragma unroll
      for (int mi = 0; mi < 4; mi++)
        #pragma unroll
        for (int ni = 0; ni < 4; ni++)
          acc[mi][ni] = MFMA_F16(af[mi], bf[ni], acc[mi][ni]);
    }
    __syncthreads();
  }
  if (z == 2) {
    // V permuted-transposed write, half4 per (mi,ni)
    #pragma unroll
    for (int mi = 0; mi < 4; mi++) {
      const int row = tm + wr * 64 + mi * 16 + 4 * lg;   // token index (j adds 0..3)
      const int n = row >> 11;
      const int s0 = (row & 2047) & ~63;
      const int cb = 32 * (mi >> 1) + 8 * lg + 4 * (mi & 1);
      #pragma unroll
      for (int ni = 0; ni < 4; ni++) {
        const int d = tn + wc * 64 + ni * 16 + lr;       // feature index
        const int nb = n * 16 + (d >> 6);
        half4 hv = __builtin_convertvector(acc[mi][ni], half4);
        *(half4*)(Vg2 + ((size_t)nb * 64 + (d & 63)) * SQ + s0 + cb) = hv;
      }
    }
  } else {
    _Float16* C = (z == 0) ? C0 : C1;
    const float sc = (z == 0) ? QSCALE : 1.0f;
    #pragma unroll
    for (int mi = 0; mi < 4; mi++) {
      const int row = tm + wr * 64 + mi * 16 + 4 * lg;
      #pragma unroll
      for (int ni = 0; ni < 4; ni++) {
        const int col = tn + wc * 64 + ni * 16 + lr;
        #pragma unroll
        for (int j = 0; j < 4; j++)
          C[(size_t)(row + j) * N + col] = (_Float16)(acc[mi][ni][j] * sc);
      }
    }
  }
}

// -------- Output GEMM: 64x128 tile (512 blocks for occupancy), f32 + bias --
__global__ __launch_bounds__(256, 2)
void gemm_o(const _Float16* __restrict__ A, const _Float16* __restrict__ B,
            float* __restrict__ Cf, const float* __restrict__ bias,
            int M, int N, int K)
{
  __shared__ _Float16 As[64 * 64];    // 8 KB
  __shared__ _Float16 Bs[128 * 64];   // 16 KB
  const int tid = threadIdx.x;
  const int w = tid >> 6, lane = tid & 63;
  const int lr = lane & 15, lg = lane >> 4;
  const int l8 = lane >> 3, l7 = lane & 7;
  const int gch = l7 ^ (l8 & 7);
  const int tm = blockIdx.x * 64, tn = blockIdx.y * 128;
  const int wr = w >> 1, wc = w & 1;   // wave = 32x64 quadrant
  const int sl7 = lr & 7;

  const f32x4 zv = {0.f, 0.f, 0.f, 0.f};
  f32x4 acc[2][4];
  #pragma unroll
  for (int mi = 0; mi < 2; mi++)
    #pragma unroll
    for (int ni = 0; ni < 4; ni++) acc[mi][ni] = zv;

  for (int ks = 0; ks < K; ks += 64) {
    #pragma unroll
    for (int ci = 0; ci < 2; ci++) {          // A: 8 chunks
      int c = w + ci * 4;
      async16(A + (size_t)(tm + c * 8 + l8) * K + ks + gch * 8, (void*)(As + c * 512));
    }
    #pragma unroll
    for (int ci = 0; ci < 4; ci++) {          // B: 16 chunks
      int c = w + ci * 4;
      async16(B + (size_t)(tn + c * 8 + l8) * K + ks + gch * 8, (void*)(Bs + c * 512));
    }
    __syncthreads();
    #pragma unroll
    for (int kk = 0; kk < 2; kk++) {
      const int sl = ((kk * 4 + lg) ^ sl7) << 4;
      half8 af[2], bf[4];
      #pragma unroll
      for (int mi = 0; mi < 2; mi++)
        af[mi] = *(const half8*)((const char*)As + (wr * 32 + mi * 16 + lr) * 128 + sl);
      #pragma unroll
      for (int ni = 0; ni < 4; ni++)
        bf[ni] = *(const half8*)((const char*)Bs + (wc * 64 + ni * 16 + lr) * 128 + sl);
      #pragma unroll
      for (int mi = 0; mi < 2; mi++)
        #pragma unroll
        for (int ni = 0; ni < 4; ni++)
          acc[mi][ni] = MFMA_F16(af[mi], bf[ni], acc[mi][ni]);
    }
    __syncthreads();
  }
  #pragma unroll
  for (int mi = 0; mi < 2; mi++) {
    const int row = tm + wr * 32 + mi * 16 + 4 * lg;
    #pragma unroll
    for (int ni = 0; ni < 4; ni++) {
      const int col = tn + wc * 64 + ni * 16 + lr;
      #pragma unroll
      for (int j = 0; j < 4; j++)
        Cf[(size_t)(row + j) * N + col] = acc[mi][ni][j] + bias[col];
    }
  }
}

// -------- Flash attention, swapped-operand form, 64 Q-rows per block -------
// Grid 1024 blocks (4/CU). S^T = mfma(K, Q): lane owns q-col = lane&15 and a
// 16-value kv slice -> softmax = in-lane tree + shfl_xor(16,32). P packed
// in-register via cvt_pkrtz; PV k-mapping matched by Vg2's column permutation.
// Defer-max: skip O-rescale while the running max grows < 8 (exp2 domain).
__global__ __launch_bounds__(256, 4)
void attn_kernel(const _Float16* __restrict__ Q, const _Float16* __restrict__ Kg,
                 const _Float16* __restrict__ Vg2, _Float16* __restrict__ Og)
{
  __shared__ _Float16 Ks[2][64 * 64];
  __shared__ _Float16 Vt[2][64 * 64];
  const int tid = threadIdx.x;
  const int w = tid >> 6, lane = tid & 63;
  const int lr = lane & 15, lg = lane >> 4;
  const int l8 = lane >> 3, l7 = lane & 7;
  // bijective XCD swizzle: 1024 blocks, 128 per XCD => 4 heads per XCD L2
  const int id = blockIdx.x + 32 * blockIdx.y;
  const int wid = (id & 7) * 128 + (id >> 3);
  const int qb = wid & 31, nb = wid >> 5;
  const size_t hb  = (size_t)(nb >> 4) * SQ * E + (size_t)(nb & 15) * 64;
  const size_t hb2 = (size_t)nb * 64 * SQ;
  const int qbase = qb * 64 + w * 16;
  const int gsl = (l7 ^ (l8 & 7)) * 8;    // pre-swizzled global slot (elems)
  const int sl7 = lr & 7;

  // Q B-frags in registers (already scaled by QSCALE in the projection GEMM)
  half8 qf[2];
  #pragma unroll
  for (int kd = 0; kd < 2; kd++)
    qf[kd] = *(const half8*)(Q + hb + (size_t)(qbase + lr) * E + kd * 32 + lg * 8);

  const f32x4 zv = {0.f, 0.f, 0.f, 0.f};
  f32x4 o[4];
  float ms = -1e30f, ls = 0.f;
  #pragma unroll
  for (int nd = 0; nd < 4; nd++) o[nd] = zv;

  // prologue: stage tile 0 into buffer 0
  #pragma unroll
  for (int ci = 0; ci < 2; ci++) {
    int c = w + ci * 4;
    async16(Kg  + hb  + (size_t)(c * 8 + l8) * E  + gsl, (void*)(Ks[0] + c * 512));
    async16(Vg2 + hb2 + (size_t)(c * 8 + l8) * SQ + gsl, (void*)(Vt[0] + c * 512));
  }
  __syncthreads();

  int cur = 0;
  for (int t = 0; t < 32; t++) {
    if (t < 31) {     // issue next-tile staging early
      const int kvb = (t + 1) * 64;
      #pragma unroll
      for (int ci = 0; ci < 2; ci++) {
        int c = w + ci * 4;
        async16(Kg  + hb  + (size_t)(kvb + c * 8 + l8) * E + gsl, (void*)(Ks[cur ^ 1] + c * 512));
        async16(Vg2 + hb2 + (size_t)(c * 8 + l8) * SQ + kvb + gsl, (void*)(Vt[cur ^ 1] + c * 512));
      }
    }
    // S^T = K Q^T (exp2-domain scaled): s[ni] rows kv=16ni+4lg+j, col q=lr
    f32x4 s[4];
    #pragma unroll
    for (int ni = 0; ni < 4; ni++) s[ni] = zv;
    #pragma unroll
    for (int kd = 0; kd < 2; kd++) {
      const int sl = ((kd * 4 + lg) ^ sl7) << 4;
      half8 kf[4];
      #pragma unroll
      for (int ni = 0; ni < 4; ni++)
        kf[ni] = *(const half8*)((const char*)Ks[cur] + (ni * 16 + lr) * 128 + sl);
      #pragma unroll
      for (int ni = 0; ni < 4; ni++)
        s[ni] = MFMA_F16(kf[ni], qf[kd], s[ni]);
    }
    // online softmax (exp2 domain), defer-max
    {
      float m0 = fmaxf(fmaxf(s[0][0], s[0][1]), fmaxf(s[0][2], s[0][3]));
      float m1 = fmaxf(fmaxf(s[1][0], s[1][1]), fmaxf(s[1][2], s[1][3]));
      float m2 = fmaxf(fmaxf(s[2][0], s[2][1]), fmaxf(s[2][2], s[2][3]));
      float m3 = fmaxf(fmaxf(s[3][0], s[3][1]), fmaxf(s[3][2], s[3][3]));
      float mx = fmaxf(fmaxf(m0, m1), fmaxf(m2, m3));
      mx = fmaxf(mx, __shfl_xor(mx, 16));
      mx = fmaxf(mx, __shfl_xor(mx, 32));
      if (__all(mx <= ms + 8.0f)) {
        // keep old max; P bounded by 2^8
        float rs = 0.f;
        #pragma unroll
        for (int ni = 0; ni < 4; ni++)
          #pragma unroll
          for (int jr = 0; jr < 4; jr++) {
            float p = EXP2(s[ni][jr] - ms);
            s[ni][jr] = p; rs += p;
          }
        rs += __shfl_xor(rs, 16);
        rs += __shfl_xor(rs, 32);
        ls += rs;
      } else {
        float mnew = fmaxf(ms, mx);
        float corr = EXP2(ms - mnew);
        ms = mnew;
        float rs = 0.f;
        #pragma unroll
        for (int ni = 0; ni < 4; ni++)
          #pragma unroll
          for (int jr = 0; jr < 4; jr++) {
            float p = EXP2(s[ni][jr] - ms);
            s[ni][jr] = p; rs += p;
          }
        rs += __shfl_xor(rs, 16);
        rs += __shfl_xor(rs, 32);
        ls = ls * corr + rs;
        // rescale O: corr lives at lane q=lr; O-row q = 4lg+jr
        #pragma unroll
        for (int jr = 0; jr < 4; jr++) {
          float c4 = bperm_f(4 * lg + jr, corr);
          #pragma unroll
          for (int nd = 0; nd < 4; nd++) o[nd][jr] *= c4;
        }
      }
    }
    // pack P A-frags in-lane via cvt_pkrtz: k-slot j' at kk -> kv = 32kk+16(j'>>2)+4lg+(j'&3)
    half8 pa[2];
    #pragma unroll
    for (int kk = 0; kk < 2; kk++) {
      union { half8 h8; fp16x2 h2[4]; } u;
      u.h2[0] = __builtin_amdgcn_cvt_pkrtz(s[2 * kk][0], s[2 * kk][1]);
      u.h2[1] = __builtin_amdgcn_cvt_pkrtz(s[2 * kk][2], s[2 * kk][3]);
      u.h2[2] = __builtin_amdgcn_cvt_pkrtz(s[2 * kk + 1][0], s[2 * kk + 1][1]);
      u.h2[3] = __builtin_amdgcn_cvt_pkrtz(s[2 * kk + 1][2], s[2 * kk + 1][3]);
      pa[kk] = u.h8;
    }
    // O += P V  (B-frags from permuted Vt; same read pattern as kf)
    #pragma unroll
    for (int kk = 0; kk < 2; kk++) {
      const int sl = ((kk * 4 + lg) ^ sl7) << 4;
      half8 vf[4];
      #pragma unroll
      for (int nd = 0; nd < 4; nd++)
        vf[nd] = *(const half8*)((const char*)Vt[cur] + (nd * 16 + lr) * 128 + sl);
      #pragma unroll
      for (int nd = 0; nd < 4; nd++)
        o[nd] = MFMA_F16(pa[kk], vf[nd], o[nd]);
    }
    __syncthreads();
    cur ^= 1;
  }
  // epilogue: O /= l (1/l redistributed like corr)
  {
    float li = 1.0f / ls;
    #pragma unroll
    for (int jr = 0; jr < 4; jr++) {
      float lv = bperm_f(4 * lg + jr, li);
      const int row = qbase + 4 * lg + jr;
      #pragma unroll
      for (int nd = 0; nd < 4; nd++)
        Og[hb + (size_t)row * E + nd * 16 + lr] = (_Float16)(o[nd][jr] * lv);
    }
  }
}

extern "C" void kernel_launch(void* const* d_in, const int* in_sizes, int n_in,
                              void* d_out, int out_size, void* d_ws, size_t ws_size,
                              hipStream_t stream)
{
  const float* x  = (const float*)d_in[0];
  const float* Wq = (const float*)d_in[1];
  const float* Wk = (const float*)d_in[2];
  const float* Wv = (const float*)d_in[3];
  const float* Wo = (const float*)d_in[4];
  const float* bo = (const float*)d_in[5];
  char* ws = (char*)d_ws;
  const size_t MB = 1024u * 1024u;
  // ws layout (32 MiB): [0,8) xh | [8,16) weights f16 | [16,24) Vg2 | [24,32) Oh
  _Float16* xh  = (_Float16*)(ws);
  _Float16* Wqh = (_Float16*)(ws + 8 * MB);
  _Float16* Wkh = (_Float16*)(ws + 10 * MB);
  _Float16* Wvh = (_Float16*)(ws + 12 * MB);
  _Float16* Woh = (_Float16*)(ws + 14 * MB);
  _Float16* Vg2 = (_Float16*)(ws + 16 * MB);
  _Float16* Oh  = (_Float16*)(ws + 24 * MB);
  // Q and K parked in d_out (dead before final GEMM overwrites it)
  _Float16* Qh  = (_Float16*)(d_out);
  _Float16* Kh  = (_Float16*)((char*)d_out + 8 * MB);
  float* Y = (float*)d_out;

  cvtall<<<8192, 256, 0, stream>>>(x, Wq, Wk, Wv, Wo, xh, Wqh, Wkh, Wvh, Woh);

  gemm_qkv<<<dim3(32, 8, 3), 256, 0, stream>>>(
      xh, Wqh, Wkh, Wvh, Qh, Kh, Vg2, NR, E, E);

  attn_kernel<<<dim3(32, 32), 256, 0, stream>>>(Qh, Kh, Vg2, Oh);

  gemm_o<<<dim3(64, 8), 256, 0, stream>>>(Oh, Woh, Y, bo, NR, E, E);
}